// Round 1
// baseline (961.991 us; speedup 1.0000x reference)
//
#include <hip/hip_runtime.h>
#include <hip/hip_bf16.h>

#define D_MODEL 768
#define D_INNER 1536
#define D_STATE 16
#define DT_RANK 48
#define D_CONV 4
#define BB 2
#define LL 2048
#define BL (BB*LL)   // 4096
#define NCHUNK 16
#define CHUNK (LL/NCHUNK)  // 128

// ---------------- tiled fp32 GEMM ----------------
// C[M,N] = A[M,K] @ B[K,N]. Output cols < splitN -> C0, else C1 (col-splitN),
// both with leading dim ldc. All dims divisible by tile sizes.
#define GBM 128
#define GBN 128
#define GBK 16

__global__ __launch_bounds__(256) void gemm_f32(
    const float* __restrict__ A, const float* __restrict__ B,
    float* __restrict__ C0, float* __restrict__ C1,
    int splitN, int ldc, int M, int N, int K)
{
  __shared__ float As[GBK][GBM + 4];
  __shared__ float Bs[GBK][GBN + 4];
  const int tid  = threadIdx.x;
  const int row0 = blockIdx.y * GBM;
  const int col0 = blockIdx.x * GBN;
  const int arow = tid >> 1, akb = (tid & 1) * 8;   // A: 128 rows x 16 k, 8/thread
  const int bkk  = tid >> 4, bcb = (tid & 15) * 8;  // B: 16 k x 128 cols, 8/thread
  const int ty   = tid >> 4, tx  = tid & 15;

  float acc[8][8];
  #pragma unroll
  for (int i = 0; i < 8; ++i)
    #pragma unroll
    for (int j = 0; j < 8; ++j) acc[i][j] = 0.f;

  for (int k0 = 0; k0 < K; k0 += GBK) {
    const float* ap = A + (size_t)(row0 + arow) * K + (k0 + akb);
    float4 a0 = *(const float4*)ap;
    float4 a1 = *(const float4*)(ap + 4);
    const float* bp = B + (size_t)(k0 + bkk) * N + (col0 + bcb);
    float4 b0 = *(const float4*)bp;
    float4 b1 = *(const float4*)(bp + 4);

    As[akb + 0][arow] = a0.x; As[akb + 1][arow] = a0.y;
    As[akb + 2][arow] = a0.z; As[akb + 3][arow] = a0.w;
    As[akb + 4][arow] = a1.x; As[akb + 5][arow] = a1.y;
    As[akb + 6][arow] = a1.z; As[akb + 7][arow] = a1.w;
    *(float4*)&Bs[bkk][bcb]     = b0;
    *(float4*)&Bs[bkk][bcb + 4] = b1;
    __syncthreads();

    #pragma unroll
    for (int kk = 0; kk < GBK; ++kk) {
      float a[8], b[8];
      *(float4*)&a[0] = *(const float4*)&As[kk][ty * 8];
      *(float4*)&a[4] = *(const float4*)&As[kk][ty * 8 + 4];
      *(float4*)&b[0] = *(const float4*)&Bs[kk][tx * 8];
      *(float4*)&b[4] = *(const float4*)&Bs[kk][tx * 8 + 4];
      #pragma unroll
      for (int i = 0; i < 8; ++i)
        #pragma unroll
        for (int j = 0; j < 8; ++j) acc[i][j] += a[i] * b[j];
    }
    __syncthreads();
  }

  float* Cp; int cadj;
  if (col0 < splitN) { Cp = C0; cadj = 0; } else { Cp = C1; cadj = splitN; }
  #pragma unroll
  for (int i = 0; i < 8; ++i) {
    int r = row0 + ty * 8 + i;
    float* cp = Cp + (size_t)r * ldc + (col0 - cadj) + tx * 8;
    float4 v0 = make_float4(acc[i][0], acc[i][1], acc[i][2], acc[i][3]);
    float4 v1 = make_float4(acc[i][4], acc[i][5], acc[i][6], acc[i][7]);
    *(float4*)cp = v0;
    *(float4*)(cp + 4) = v1;
  }
}

// ---------------- causal depthwise conv (width 4) + SiLU ----------------
__global__ __launch_bounds__(256) void conv_silu_kernel(
    const float* __restrict__ u_raw, const float* __restrict__ cw,
    const float* __restrict__ cb, float* __restrict__ u)
{
  int idx = blockIdx.x * 256 + threadIdx.x;  // over BL*D_INNER
  int d  = idx % D_INNER;
  int bl = idx / D_INNER;
  int l  = bl % LL;
  float acc = cb[d];
  #pragma unroll
  for (int k = 0; k < D_CONV; ++k) {
    int ls = l - (D_CONV - 1) + k;
    if (ls >= 0) acc += u_raw[idx + (k - (D_CONV - 1)) * D_INNER] * cw[d * D_CONV + k];
  }
  u[idx] = acc / (1.f + __expf(-acc));
}

// ---------------- x_dbl = u @ W_x  (K=1536, N=80) ----------------
// 8 rows per block, W_x K-tile staged in LDS.
__global__ __launch_bounds__(256) void xdbl_kernel(
    const float* __restrict__ u, const float* __restrict__ Wx,
    float* __restrict__ xd)
{
  __shared__ float Ws[128 * 80];
  __shared__ float Us[8 * 128];
  const int m0 = blockIdx.x * 8;
  const int tid = threadIdx.x;
  float acc[8] = {0.f,0.f,0.f,0.f,0.f,0.f,0.f,0.f};
  for (int k0 = 0; k0 < D_INNER; k0 += 128) {
    __syncthreads();
    for (int f = tid; f < 128 * 80; f += 256) Ws[f] = Wx[k0 * 80 + f];  // rows contiguous
    for (int f = tid; f < 8 * 128; f += 256)
      Us[f] = u[(size_t)(m0 + (f >> 7)) * D_INNER + k0 + (f & 127)];
    __syncthreads();
    if (tid < 80) {
      for (int kk = 0; kk < 128; ++kk) {
        float w = Ws[kk * 80 + tid];
        #pragma unroll
        for (int r = 0; r < 8; ++r) acc[r] += Us[r * 128 + kk] * w;
      }
    }
  }
  if (tid < 80) {
    #pragma unroll
    for (int r = 0; r < 8; ++r) xd[(size_t)(m0 + r) * 80 + tid] = acc[r];
  }
}

// ---------------- delta = softplus(xdbl[:, :48] @ W_dt + b_dt) ----------------
// block: 16 rows x 256 cols
__global__ __launch_bounds__(256) void delta_kernel(
    const float* __restrict__ xd, const float* __restrict__ Wdt,
    const float* __restrict__ bdt, float* __restrict__ delta)
{
  __shared__ float As[16][DT_RANK];
  __shared__ float Ws[DT_RANK][256];
  const int n0 = blockIdx.x * 256;
  const int m0 = blockIdx.y * 16;
  const int tid = threadIdx.x;
  for (int f = tid; f < 16 * DT_RANK; f += 256)
    As[f / DT_RANK][f % DT_RANK] = xd[(size_t)(m0 + f / DT_RANK) * 80 + (f % DT_RANK)];
  for (int f = tid; f < DT_RANK * 256; f += 256)
    Ws[f >> 8][f & 255] = Wdt[(size_t)(f >> 8) * D_INNER + n0 + (f & 255)];
  __syncthreads();
  float acc[16];
  #pragma unroll
  for (int i = 0; i < 16; ++i) acc[i] = 0.f;
  for (int k = 0; k < DT_RANK; ++k) {
    float w = Ws[k][tid];
    #pragma unroll
    for (int i = 0; i < 16; ++i) acc[i] += As[i][k] * w;
  }
  float bb = bdt[n0 + tid];
  #pragma unroll
  for (int i = 0; i < 16; ++i) {
    float v = acc[i] + bb;
    float sp = fmaxf(v, 0.f) + log1pf(__expf(-fabsf(v)));
    delta[(size_t)(m0 + i) * D_INNER + n0 + tid] = sp;
  }
}

// ---------------- chunked selective scan ----------------
// lane layout: g = ((b*D_INNER + d)*NCHUNK + c)*16 + n  (n fastest, 16-aligned)
__global__ __launch_bounds__(256) void scan_pass1(
    const float* __restrict__ delta, const float* __restrict__ u,
    const float* __restrict__ xd, const float* __restrict__ A_log,
    float* __restrict__ prodA, float* __restrict__ localS)
{
  int g = blockIdx.x * 256 + threadIdx.x;
  int n = g & 15;
  int c = (g >> 4) & (NCHUNK - 1);
  int bd = g >> 8;                 // b*D_INNER + d
  int b = bd / D_INNER;
  int d = bd - b * D_INNER;
  float Aneg = -__expf(A_log[d * D_STATE + n]);
  int t0 = c * CHUNK;
  size_t pdu = ((size_t)b * LL + t0) * D_INNER + d;
  size_t px  = ((size_t)b * LL + t0) * 80 + DT_RANK + n;
  float prod = 1.f, s = 0.f;
  for (int tt = 0; tt < CHUNK; ++tt) {
    float dt = delta[pdu];
    float ut = u[pdu];
    float Bn = xd[px];
    float da = __expf(dt * Aneg);
    prod *= da;
    s = da * s + dt * Bn * ut;
    pdu += D_INNER; px += 80;
  }
  size_t idx = ((size_t)bd * 16 + n) * NCHUNK + c;
  prodA[idx]  = prod;
  localS[idx] = s;
}

__global__ __launch_bounds__(256) void scan_pass2(
    const float* __restrict__ prodA, const float* __restrict__ localS,
    float* __restrict__ sIn)
{
  int g = blockIdx.x * 256 + threadIdx.x;  // b*D_INNER*16 lanes
  size_t base = (size_t)g * NCHUNK;
  float s = 0.f;
  for (int c = 0; c < NCHUNK; ++c) {
    sIn[base + c] = s;
    s = prodA[base + c] * s + localS[base + c];
  }
}

__global__ __launch_bounds__(256) void scan_pass3(
    const float* __restrict__ delta, const float* __restrict__ u,
    const float* __restrict__ xd, const float* __restrict__ A_log,
    const float* __restrict__ sIn, float* __restrict__ ysc)
{
  int g = blockIdx.x * 256 + threadIdx.x;
  int n = g & 15;
  int c = (g >> 4) & (NCHUNK - 1);
  int bd = g >> 8;
  int b = bd / D_INNER;
  int d = bd - b * D_INNER;
  float Aneg = -__expf(A_log[d * D_STATE + n]);
  int t0 = c * CHUNK;
  size_t pdu = ((size_t)b * LL + t0) * D_INNER + d;
  size_t px  = ((size_t)b * LL + t0) * 80 + DT_RANK + n;
  float s = sIn[((size_t)bd * 16 + n) * NCHUNK + c];
  for (int tt = 0; tt < CHUNK; ++tt) {
    float dt = delta[pdu];
    float ut = u[pdu];
    float Bn = xd[px];
    float Cn = xd[px + D_STATE];
    float da = __expf(dt * Aneg);
    s = da * s + dt * Bn * ut;
    float p = s * Cn;
    p += __shfl_xor(p, 1);
    p += __shfl_xor(p, 2);
    p += __shfl_xor(p, 4);
    p += __shfl_xor(p, 8);
    if (n == 0) ysc[pdu] = p;
    pdu += D_INNER; px += 80;
  }
}

// ---------------- y = (ysc + u*Dp) * silu(res) ----------------
__global__ __launch_bounds__(256) void combine_kernel(
    const float* __restrict__ ysc, const float* __restrict__ u,
    const float* __restrict__ Dp, const float* __restrict__ res,
    float* __restrict__ y)
{
  int idx = blockIdx.x * 256 + threadIdx.x;
  int d = idx % D_INNER;
  float r = res[idx];
  float sr = r / (1.f + __expf(-r));
  y[idx] = (ysc[idx] + u[idx] * Dp[d]) * sr;
}

extern "C" void kernel_launch(void* const* d_in, const int* in_sizes, int n_in,
                              void* d_out, int out_size, void* d_ws, size_t ws_size,
                              hipStream_t stream) {
  const float* x      = (const float*)d_in[0];
  const float* W_in   = (const float*)d_in[1];
  const float* conv_w = (const float*)d_in[2];
  const float* conv_b = (const float*)d_in[3];
  const float* W_x    = (const float*)d_in[4];
  const float* W_dt   = (const float*)d_in[5];
  const float* b_dt   = (const float*)d_in[6];
  const float* A_log  = (const float*)d_in[7];
  const float* Dp     = (const float*)d_in[8];
  const float* W_out  = (const float*)d_in[9];
  float* out = (float*)d_out;

  float* ws     = (float*)d_ws;
  float* u_raw  = ws;                               // BL*D_INNER
  float* res    = u_raw  + (size_t)BL * D_INNER;    // BL*D_INNER
  float* u      = res    + (size_t)BL * D_INNER;    // BL*D_INNER
  float* xd     = u      + (size_t)BL * D_INNER;    // BL*80
  float* delta  = xd     + (size_t)BL * 80;         // BL*D_INNER
  float* ysc    = delta  + (size_t)BL * D_INNER;    // BL*D_INNER
  float* prodA  = ysc    + (size_t)BL * D_INNER;    // BB*D_INNER*16*NCHUNK
  float* localS = prodA  + (size_t)BB * D_INNER * 16 * NCHUNK;
  float* sIn    = localS + (size_t)BB * D_INNER * 16 * NCHUNK;

  // 1) x @ W_in -> [u_raw | res]
  gemm_f32<<<dim3((2 * D_INNER) / GBN, BL / GBM), 256, 0, stream>>>(
      x, W_in, u_raw, res, D_INNER, D_INNER, BL, 2 * D_INNER, D_MODEL);
  // 2) causal conv + silu
  conv_silu_kernel<<<(BL * D_INNER) / 256, 256, 0, stream>>>(u_raw, conv_w, conv_b, u);
  // 3) x_dbl = u @ W_x
  xdbl_kernel<<<BL / 8, 256, 0, stream>>>(u, W_x, xd);
  // 4) delta
  delta_kernel<<<dim3(D_INNER / 256, BL / 16), 256, 0, stream>>>(xd, W_dt, b_dt, delta);
  // 5) chunked scan
  int scan_threads = BB * D_INNER * NCHUNK * 16;   // 786432
  scan_pass1<<<scan_threads / 256, 256, 0, stream>>>(delta, u, xd, A_log, prodA, localS);
  scan_pass2<<<(BB * D_INNER * 16) / 256, 256, 0, stream>>>(prodA, localS, sIn);
  scan_pass3<<<scan_threads / 256, 256, 0, stream>>>(delta, u, xd, A_log, sIn, ysc);
  // 6) combine elementwise (in-place into ysc)
  combine_kernel<<<(BL * D_INNER) / 256, 256, 0, stream>>>(ysc, u, Dp, res, ysc);
  // 7) out = y @ W_out
  gemm_f32<<<dim3(D_MODEL / GBN, BL / GBM), 256, 0, stream>>>(
      ysc, W_out, out, nullptr, D_MODEL, D_MODEL, BL, D_MODEL, D_INNER);
}

// Round 2
// 444.784 us; speedup vs baseline: 2.1628x; 2.1628x over previous
//
#include <hip/hip_runtime.h>
#include <hip/hip_bf16.h>

#define D_MODEL 768
#define D_INNER 1536
#define D_STATE 16
#define DT_RANK 48
#define D_CONV 4
#define BB 2
#define LL 2048
#define BL (BB*LL)   // 4096
#define NCHUNK 16
#define CHUNK (LL/NCHUNK)  // 128

typedef unsigned short ushort_t;
typedef __attribute__((ext_vector_type(8))) short bhalf8;
typedef __attribute__((ext_vector_type(4))) float f32x4;
typedef __attribute__((address_space(3))) unsigned char lds_b;
typedef __attribute__((address_space(1))) const unsigned char glob_b;

// ================= bf16 MFMA GEMM (m97 structure) =================
// C[M,N] = A[M,K] @ B[K,N]; A bf16 [M][K] row-major, BT bf16 [N][K] row-major.
// Output split at column splitN into C0/C1 (both ldc), fp32. Cols >= Nreal
// (per-half space) dropped. M%128==0, N%128==0, K%32==0.
#define TM 128
#define TN 128
#define TK 32

__global__ __launch_bounds__(256) void gemm_bf16(
    const ushort_t* __restrict__ A, const ushort_t* __restrict__ BT,
    float* __restrict__ C0, float* __restrict__ C1,
    int splitN, int ldc, int Nreal, int M, int N, int K)
{
  __shared__ ushort_t As[TM * TK];   // row-major [128][32] bf16
  __shared__ ushort_t Bs[TN * TK];
  const int tid  = threadIdx.x;
  const int row0 = blockIdx.y * TM;
  const int col0 = blockIdx.x * TN;
  const int lane = tid & 63, wave = tid >> 6;
  const int wy = wave >> 1, wx = wave & 1;
  const int mm = lane & 15, quad = lane >> 4;

  f32x4 acc[4][4];
  #pragma unroll
  for (int i = 0; i < 4; ++i)
    #pragma unroll
    for (int j = 0; j < 4; ++j)
      acc[i][j] = (f32x4){0.f, 0.f, 0.f, 0.f};

  const int c0id = tid, c1id = tid + 256;  // 512 chunks of 16B per 8KB tile
  const int r0a = c0id >> 2, k0a = (c0id & 3) * 8;
  const int r1a = c1id >> 2, k1a = (c1id & 3) * 8;

  for (int k0 = 0; k0 < K; k0 += TK) {
    __syncthreads();  // readers of previous tile done
    {
      const ushort_t* g0 = A + (size_t)(row0 + r0a) * K + k0 + k0a;
      const ushort_t* g1 = A + (size_t)(row0 + r1a) * K + k0 + k1a;
      __builtin_amdgcn_global_load_lds((glob_b*)g0, (lds_b*)&As[c0id * 8], 16, 0, 0);
      __builtin_amdgcn_global_load_lds((glob_b*)g1, (lds_b*)&As[c1id * 8], 16, 0, 0);
      const ushort_t* h0 = BT + (size_t)(col0 + r0a) * K + k0 + k0a;
      const ushort_t* h1 = BT + (size_t)(col0 + r1a) * K + k0 + k1a;
      __builtin_amdgcn_global_load_lds((glob_b*)h0, (lds_b*)&Bs[c0id * 8], 16, 0, 0);
      __builtin_amdgcn_global_load_lds((glob_b*)h1, (lds_b*)&Bs[c1id * 8], 16, 0, 0);
    }
    __syncthreads();  // barrier drains vmcnt -> LDS populated

    bhalf8 af[4], bfr[4];
    #pragma unroll
    for (int i = 0; i < 4; ++i)
      af[i] = *(const bhalf8*)&As[(wy * 64 + i * 16 + mm) * TK + quad * 8];
    #pragma unroll
    for (int j = 0; j < 4; ++j)
      bfr[j] = *(const bhalf8*)&Bs[(wx * 64 + j * 16 + mm) * TK + quad * 8];
    #pragma unroll
    for (int i = 0; i < 4; ++i)
      #pragma unroll
      for (int j = 0; j < 4; ++j)
        acc[i][j] = __builtin_amdgcn_mfma_f32_16x16x32_bf16(af[i], bfr[j], acc[i][j], 0, 0, 0);
  }

  const int coff = (col0 < splitN) ? 0 : splitN;
  float* Cp = (col0 < splitN) ? C0 : C1;
  #pragma unroll
  for (int i = 0; i < 4; ++i) {
    const int row = row0 + wy * 64 + i * 16 + quad * 4;
    #pragma unroll
    for (int j = 0; j < 4; ++j) {
      const int col = col0 - coff + wx * 64 + j * 16 + mm;
      if (col < Nreal) {
        #pragma unroll
        for (int r = 0; r < 4; ++r)
          Cp[(size_t)(row + r) * ldc + col] = acc[i][j][r];
      }
    }
  }
}

// ================= fp32 -> bf16 transpose: out[Cpad][R] = in[R][C]^T =======
__global__ __launch_bounds__(256) void transpose_cvt(
    const float* __restrict__ in, __hip_bfloat16* __restrict__ out,
    int R, int C, int Cpad)
{
  __shared__ __hip_bfloat16 tile[32][33];
  const int c0 = blockIdx.x * 32, r0 = blockIdx.y * 32;
  const int tx = threadIdx.x & 31, ty = threadIdx.x >> 5;
  #pragma unroll
  for (int i = 0; i < 32; i += 8) {
    const int c = c0 + tx;
    float v = (c < C) ? in[(size_t)(r0 + ty + i) * C + c] : 0.f;
    tile[ty + i][tx] = __float2bfloat16(v);
  }
  __syncthreads();
  #pragma unroll
  for (int i = 0; i < 32; i += 8)
    out[(size_t)(c0 + ty + i) * R + r0 + tx] = tile[tx][ty + i];
}

// ================= fp32 -> bf16 elementwise =================
__global__ __launch_bounds__(256) void cvt_bf16(
    const float* __restrict__ in, __hip_bfloat16* __restrict__ out)
{
  const int i = (blockIdx.x * 256 + threadIdx.x) * 4;
  float4 v = *(const float4*)(in + i);
  out[i]     = __float2bfloat16(v.x);
  out[i + 1] = __float2bfloat16(v.y);
  out[i + 2] = __float2bfloat16(v.z);
  out[i + 3] = __float2bfloat16(v.w);
}

// ============ causal depthwise conv (width 4) + SiLU, dual output ==========
__global__ __launch_bounds__(256) void conv_silu_kernel(
    const float* __restrict__ u_raw, const float* __restrict__ cw,
    const float* __restrict__ cb, float* __restrict__ u,
    __hip_bfloat16* __restrict__ ub)
{
  const int idx = blockIdx.x * 256 + threadIdx.x;  // over BL*D_INNER
  const int d  = idx % D_INNER;
  const int bl = idx / D_INNER;
  const int l  = bl % LL;
  float acc = cb[d];
  #pragma unroll
  for (int k = 0; k < D_CONV; ++k) {
    const int ls = l - (D_CONV - 1) + k;
    if (ls >= 0) acc += u_raw[idx + (k - (D_CONV - 1)) * D_INNER] * cw[d * D_CONV + k];
  }
  const float s = acc / (1.f + __expf(-acc));
  u[idx]  = s;
  ub[idx] = __float2bfloat16(s);
}

// ======== delta = softplus(xd[:, :48] @ W_dt + b_dt), fp32 ========
__global__ __launch_bounds__(256) void delta_kernel(
    const float* __restrict__ xd, const float* __restrict__ Wdt,
    const float* __restrict__ bdt, float* __restrict__ delta)
{
  __shared__ float Asr[16][DT_RANK];
  __shared__ float Ws[DT_RANK][256];
  const int n0 = blockIdx.x * 256;
  const int m0 = blockIdx.y * 16;
  const int tid = threadIdx.x;
  for (int f = tid; f < 16 * DT_RANK; f += 256)
    Asr[f / DT_RANK][f % DT_RANK] = xd[(size_t)(m0 + f / DT_RANK) * 80 + (f % DT_RANK)];
  for (int f = tid; f < DT_RANK * 256; f += 256)
    Ws[f >> 8][f & 255] = Wdt[(size_t)(f >> 8) * D_INNER + n0 + (f & 255)];
  __syncthreads();
  float acc[16];
  #pragma unroll
  for (int i = 0; i < 16; ++i) acc[i] = 0.f;
  for (int k = 0; k < DT_RANK; ++k) {
    const float w = Ws[k][tid];
    #pragma unroll
    for (int i = 0; i < 16; ++i) acc[i] += Asr[i][k] * w;
  }
  const float bb = bdt[n0 + tid];
  #pragma unroll
  for (int i = 0; i < 16; ++i) {
    const float v = acc[i] + bb;
    delta[(size_t)(m0 + i) * D_INNER + n0 + tid] =
        fmaxf(v, 0.f) + log1pf(__expf(-fabsf(v)));
  }
}

// ================= chunked selective scan, LDS-staged =================
// grid: (NCHUNK, D_INNER/16, BB); block 256 = 16 d x 16 n; lane = dl*16+n.
__global__ __launch_bounds__(256) void scan_pass1(
    const float* __restrict__ delta, const float* __restrict__ u,
    const float* __restrict__ xd, const float* __restrict__ A_log,
    float* __restrict__ prodA, float* __restrict__ localS)
{
  __shared__ float ds[CHUNK][16], us[CHUNK][16], Bsh[CHUNK][16];
  const int c = blockIdx.x, dg = blockIdx.y, b = blockIdx.z;
  const int d0 = dg * 16, t0 = c * CHUNK;
  const int tid = threadIdx.x;
  {
    const float* dbase = delta + ((size_t)b * LL + t0) * D_INNER + d0;
    const float* ubase = u     + ((size_t)b * LL + t0) * D_INNER + d0;
    const float* xbase = xd    + ((size_t)b * LL + t0) * 80 + DT_RANK;
    #pragma unroll
    for (int i = 0; i < 2; ++i) {
      const int f = tid + 256 * i;       // 512 float4 slots
      const int t = f >> 2, dq = (f & 3) * 4;
      *(float4*)&ds[t][dq]  = *(const float4*)(dbase + (size_t)t * D_INNER + dq);
      *(float4*)&us[t][dq]  = *(const float4*)(ubase + (size_t)t * D_INNER + dq);
      *(float4*)&Bsh[t][dq] = *(const float4*)(xbase + (size_t)t * 80 + dq);
    }
  }
  __syncthreads();
  const int n = tid & 15, dl = tid >> 4;
  const float Aneg = -__expf(A_log[(d0 + dl) * D_STATE + n]);
  float prod = 1.f, s = 0.f;
  for (int t = 0; t < CHUNK; ++t) {
    const float dt = ds[t][dl], ut = us[t][dl], Bn = Bsh[t][n];
    const float da = __expf(dt * Aneg);
    prod *= da;
    s = da * s + dt * Bn * ut;
  }
  const int bd = b * D_INNER + d0 + dl;
  const size_t idx = ((size_t)bd * 16 + n) * NCHUNK + c;
  prodA[idx]  = prod;
  localS[idx] = s;
}

__global__ __launch_bounds__(256) void scan_pass2(
    const float* __restrict__ prodA, const float* __restrict__ localS,
    float* __restrict__ sIn)
{
  const int g = blockIdx.x * 256 + threadIdx.x;  // BB*D_INNER*16 lanes
  const size_t base = (size_t)g * NCHUNK;
  float s = 0.f;
  for (int c = 0; c < NCHUNK; ++c) {
    sIn[base + c] = s;
    s = prodA[base + c] * s + localS[base + c];
  }
}

// pass3: recompute from correct s_in, fused combine epilogue -> y bf16
__global__ __launch_bounds__(256) void scan_pass3(
    const float* __restrict__ delta, const float* __restrict__ u,
    const float* __restrict__ xd, const float* __restrict__ A_log,
    const float* __restrict__ sIn, const float* __restrict__ res,
    const float* __restrict__ Dp, __hip_bfloat16* __restrict__ y)
{
  __shared__ float ds[CHUNK][16], us[CHUNK][16], Bsh[CHUNK][16],
                   Cs[CHUNK][16], rs[CHUNK][16];
  __shared__ __hip_bfloat16 ys[CHUNK][16];
  const int c = blockIdx.x, dg = blockIdx.y, b = blockIdx.z;
  const int d0 = dg * 16, t0 = c * CHUNK;
  const int tid = threadIdx.x;
  {
    const float* dbase = delta + ((size_t)b * LL + t0) * D_INNER + d0;
    const float* ubase = u     + ((size_t)b * LL + t0) * D_INNER + d0;
    const float* rbase = res   + ((size_t)b * LL + t0) * D_INNER + d0;
    const float* xbase = xd    + ((size_t)b * LL + t0) * 80 + DT_RANK;
    #pragma unroll
    for (int i = 0; i < 2; ++i) {
      const int f = tid + 256 * i;
      const int t = f >> 2, dq = (f & 3) * 4;
      *(float4*)&ds[t][dq]  = *(const float4*)(dbase + (size_t)t * D_INNER + dq);
      *(float4*)&us[t][dq]  = *(const float4*)(ubase + (size_t)t * D_INNER + dq);
      *(float4*)&rs[t][dq]  = *(const float4*)(rbase + (size_t)t * D_INNER + dq);
      *(float4*)&Bsh[t][dq] = *(const float4*)(xbase + (size_t)t * 80 + dq);
      *(float4*)&Cs[t][dq]  = *(const float4*)(xbase + (size_t)t * 80 + D_STATE + dq);
    }
  }
  __syncthreads();
  const int n = tid & 15, dl = tid >> 4;
  const float Aneg = -__expf(A_log[(d0 + dl) * D_STATE + n]);
  const float Dpv  = Dp[d0 + dl];
  const int bd = b * D_INNER + d0 + dl;
  float s = sIn[((size_t)bd * 16 + n) * NCHUNK + c];
  for (int t = 0; t < CHUNK; ++t) {
    const float dt = ds[t][dl], ut = us[t][dl];
    const float da = __expf(dt * Aneg);
    s = da * s + dt * Bsh[t][n] * ut;
    float p = s * Cs[t][n];
    p += __shfl_xor(p, 1);
    p += __shfl_xor(p, 2);
    p += __shfl_xor(p, 4);
    p += __shfl_xor(p, 8);
    if (n == 0) {
      const float r = rs[t][dl];
      const float sr = r / (1.f + __expf(-r));
      ys[t][dl] = __float2bfloat16((p + ut * Dpv) * sr);
    }
  }
  __syncthreads();
  // cooperative coalesced write: 2048 bf16, 8 per thread
  const int t = tid >> 1, h = (tid & 1) * 8;
  *(uint4*)&y[((size_t)b * LL + t0 + t) * D_INNER + d0 + h] = *(const uint4*)&ys[t][h];
}

extern "C" void kernel_launch(void* const* d_in, const int* in_sizes, int n_in,
                              void* d_out, int out_size, void* d_ws, size_t ws_size,
                              hipStream_t stream) {
  const float* x      = (const float*)d_in[0];
  const float* W_in   = (const float*)d_in[1];
  const float* conv_w = (const float*)d_in[2];
  const float* conv_b = (const float*)d_in[3];
  const float* W_x    = (const float*)d_in[4];
  const float* W_dt   = (const float*)d_in[5];
  const float* b_dt   = (const float*)d_in[6];
  const float* A_log  = (const float*)d_in[7];
  const float* Dp     = (const float*)d_in[8];
  const float* W_out  = (const float*)d_in[9];
  float* out = (float*)d_out;

  // ---- workspace layout (float units), total ~135.0 MB ----
  float* ws     = (float*)d_ws;
  float* u_raw  = ws;                        // 6291456 f  (dead after conv)
  float* res    = u_raw  + 6291456;          // 6291456 f
  float* u      = res    + 6291456;          // 6291456 f
  float* delta  = u      + 6291456;          // 6291456 f
  float* xd     = delta  + 6291456;          // 327680 f
  float* prodA  = xd     + 327680;           // 786432 f
  float* localS = prodA  + 786432;           // 786432 f
  float* sIn    = localS + 786432;           // 786432 f
  __hip_bfloat16* x_bf  = (__hip_bfloat16*)(sIn + 786432);          // 3145728 bf16
  __hip_bfloat16* WinT  = (__hip_bfloat16*)(sIn + 786432 + 1572864);// 2359296 bf16
  __hip_bfloat16* u_bf  = (__hip_bfloat16*)(sIn + 786432 + 1572864 + 1179648); // 6291456 bf16
  // aliases inside dead u_raw (valid from after conv_silu onward):
  __hip_bfloat16* y_bf  = (__hip_bfloat16*)u_raw;                   // 3145728 f slots
  __hip_bfloat16* WoutT = (__hip_bfloat16*)(u_raw + 3145728);       // 589824 f slots
  __hip_bfloat16* WxT   = (__hip_bfloat16*)(u_raw + 3735552);       // 98304 f slots

  // 1) x -> bf16; W_in -> bf16^T
  cvt_bf16<<<(BL * D_MODEL) / 1024, 256, 0, stream>>>(x, x_bf);
  transpose_cvt<<<dim3(3072 / 32, 768 / 32), 256, 0, stream>>>(W_in, WinT, 768, 3072, 3072);
  // 2) GEMM1: [u_raw | res] = x @ W_in   (M=4096, N=3072, K=768)
  gemm_bf16<<<dim3(3072 / TN, BL / TM), 256, 0, stream>>>(
      (const ushort_t*)x_bf, (const ushort_t*)WinT, u_raw, res,
      D_INNER, D_INNER, D_INNER, BL, 2 * D_INNER, D_MODEL);
  // 3) conv + silu -> u fp32 + u bf16
  conv_silu_kernel<<<(BL * D_INNER) / 256, 256, 0, stream>>>(u_raw, conv_w, conv_b, u, u_bf);
  // 4) weight transposes into dead u_raw
  transpose_cvt<<<dim3(128 / 32, 1536 / 32), 256, 0, stream>>>(W_x, WxT, 1536, 80, 128);
  transpose_cvt<<<dim3(768 / 32, 1536 / 32), 256, 0, stream>>>(W_out, WoutT, 1536, 768, 768);
  // 5) GEMM2: xd = u @ W_x   (M=4096, N=128 tile / 80 real, K=1536)
  gemm_bf16<<<dim3(1, BL / TM), 256, 0, stream>>>(
      (const ushort_t*)u_bf, (const ushort_t*)WxT, xd, nullptr,
      1 << 30, 80, 80, BL, 128, D_INNER);
  // 6) delta
  delta_kernel<<<dim3(D_INNER / 256, BL / 16), 256, 0, stream>>>(xd, W_dt, b_dt, delta);
  // 7) chunked scan
  scan_pass1<<<dim3(NCHUNK, D_INNER / 16, BB), 256, 0, stream>>>(
      delta, u, xd, A_log, prodA, localS);
  scan_pass2<<<(BB * D_INNER * 16) / 256, 256, 0, stream>>>(prodA, localS, sIn);
  scan_pass3<<<dim3(NCHUNK, D_INNER / 16, BB), 256, 0, stream>>>(
      delta, u, xd, A_log, sIn, res, Dp, y_bf);
  // 8) GEMM3: out = y @ W_out   (M=4096, N=768, K=1536)
  gemm_bf16<<<dim3(768 / TN, BL / TM), 256, 0, stream>>>(
      (const ushort_t*)y_bf, (const ushort_t*)WoutT, out, nullptr,
      1 << 30, D_MODEL, D_MODEL, BL, D_MODEL, D_INNER);
}

// Round 3
// 319.556 us; speedup vs baseline: 3.0104x; 1.3919x over previous
//
#include <hip/hip_runtime.h>
#include <hip/hip_bf16.h>

#define D_MODEL 768
#define D_INNER 1536
#define D_STATE 16
#define DT_RANK 48
#define D_CONV 4
#define BB 2
#define LL 2048
#define BL (BB*LL)   // 4096
#define NCHUNK 64
#define CHUNK (LL/NCHUNK)  // 32
#define KSPLIT 8

typedef unsigned short ushort_t;
typedef __attribute__((ext_vector_type(8))) short bhalf8;
typedef __attribute__((ext_vector_type(4))) float f32x4;
typedef __attribute__((address_space(3))) unsigned char lds_b;
typedef __attribute__((address_space(1))) const unsigned char glob_b;

__device__ __forceinline__ float b2f(ushort_t v) {
  return __uint_as_float(((unsigned)v) << 16);
}

// ================= bf16 MFMA GEMM (m97 structure) =================
#define TM 128
#define TN 128
#define TK 32

__global__ __launch_bounds__(256) void gemm_bf16(
    const ushort_t* __restrict__ A, const ushort_t* __restrict__ BT,
    float* __restrict__ C0, float* __restrict__ C1,
    int splitN, int ldc, int Nreal, int M, int N, int K)
{
  __shared__ ushort_t As[TM * TK];
  __shared__ ushort_t Bs[TN * TK];
  const int tid  = threadIdx.x;
  const int row0 = blockIdx.y * TM;
  const int col0 = blockIdx.x * TN;
  const int lane = tid & 63, wave = tid >> 6;
  const int wy = wave >> 1, wx = wave & 1;
  const int mm = lane & 15, quad = lane >> 4;

  f32x4 acc[4][4];
  #pragma unroll
  for (int i = 0; i < 4; ++i)
    #pragma unroll
    for (int j = 0; j < 4; ++j)
      acc[i][j] = (f32x4){0.f, 0.f, 0.f, 0.f};

  const int c0id = tid, c1id = tid + 256;
  const int r0a = c0id >> 2, k0a = (c0id & 3) * 8;
  const int r1a = c1id >> 2, k1a = (c1id & 3) * 8;

  for (int k0 = 0; k0 < K; k0 += TK) {
    __syncthreads();
    {
      const ushort_t* g0 = A + (size_t)(row0 + r0a) * K + k0 + k0a;
      const ushort_t* g1 = A + (size_t)(row0 + r1a) * K + k0 + k1a;
      __builtin_amdgcn_global_load_lds((glob_b*)g0, (lds_b*)&As[c0id * 8], 16, 0, 0);
      __builtin_amdgcn_global_load_lds((glob_b*)g1, (lds_b*)&As[c1id * 8], 16, 0, 0);
      const ushort_t* h0 = BT + (size_t)(col0 + r0a) * K + k0 + k0a;
      const ushort_t* h1 = BT + (size_t)(col0 + r1a) * K + k0 + k1a;
      __builtin_amdgcn_global_load_lds((glob_b*)h0, (lds_b*)&Bs[c0id * 8], 16, 0, 0);
      __builtin_amdgcn_global_load_lds((glob_b*)h1, (lds_b*)&Bs[c1id * 8], 16, 0, 0);
    }
    __syncthreads();

    bhalf8 af[4], bfr[4];
    #pragma unroll
    for (int i = 0; i < 4; ++i)
      af[i] = *(const bhalf8*)&As[(wy * 64 + i * 16 + mm) * TK + quad * 8];
    #pragma unroll
    for (int j = 0; j < 4; ++j)
      bfr[j] = *(const bhalf8*)&Bs[(wx * 64 + j * 16 + mm) * TK + quad * 8];
    #pragma unroll
    for (int i = 0; i < 4; ++i)
      #pragma unroll
      for (int j = 0; j < 4; ++j)
        acc[i][j] = __builtin_amdgcn_mfma_f32_16x16x32_bf16(af[i], bfr[j], acc[i][j], 0, 0, 0);
  }

  const int coff = (col0 < splitN) ? 0 : splitN;
  float* Cp = (col0 < splitN) ? C0 : C1;
  #pragma unroll
  for (int i = 0; i < 4; ++i) {
    const int row = row0 + wy * 64 + i * 16 + quad * 4;
    #pragma unroll
    for (int j = 0; j < 4; ++j) {
      const int col = col0 - coff + wx * 64 + j * 16 + mm;
      if (col < Nreal) {
        #pragma unroll
        for (int r = 0; r < 4; ++r)
          Cp[(size_t)(row + r) * ldc + col] = acc[i][j][r];
      }
    }
  }
}

// ============ split-K GEMM for xd = u @ W_x (single 128-col tile) ==========
__global__ __launch_bounds__(256) void gemm_bf16_splitk(
    const ushort_t* __restrict__ A, const ushort_t* __restrict__ BT,
    float* __restrict__ Cpart, int Nreal, int K, int kIters)
{
  __shared__ ushort_t As[TM * TK];
  __shared__ ushort_t Bs[TN * TK];
  const int tid  = threadIdx.x;
  const int ks   = blockIdx.x;
  const int row0 = blockIdx.y * TM;
  const int lane = tid & 63, wave = tid >> 6;
  const int wy = wave >> 1, wx = wave & 1;
  const int mm = lane & 15, quad = lane >> 4;

  f32x4 acc[4][4];
  #pragma unroll
  for (int i = 0; i < 4; ++i)
    #pragma unroll
    for (int j = 0; j < 4; ++j)
      acc[i][j] = (f32x4){0.f, 0.f, 0.f, 0.f};

  const int c0id = tid, c1id = tid + 256;
  const int r0a = c0id >> 2, k0a = (c0id & 3) * 8;
  const int r1a = c1id >> 2, k1a = (c1id & 3) * 8;
  const int k0base = ks * kIters * TK;

  for (int kk = 0; kk < kIters; ++kk) {
    const int k0 = k0base + kk * TK;
    __syncthreads();
    {
      const ushort_t* g0 = A + (size_t)(row0 + r0a) * K + k0 + k0a;
      const ushort_t* g1 = A + (size_t)(row0 + r1a) * K + k0 + k1a;
      __builtin_amdgcn_global_load_lds((glob_b*)g0, (lds_b*)&As[c0id * 8], 16, 0, 0);
      __builtin_amdgcn_global_load_lds((glob_b*)g1, (lds_b*)&As[c1id * 8], 16, 0, 0);
      const ushort_t* h0 = BT + (size_t)r0a * K + k0 + k0a;
      const ushort_t* h1 = BT + (size_t)r1a * K + k0 + k1a;
      __builtin_amdgcn_global_load_lds((glob_b*)h0, (lds_b*)&Bs[c0id * 8], 16, 0, 0);
      __builtin_amdgcn_global_load_lds((glob_b*)h1, (lds_b*)&Bs[c1id * 8], 16, 0, 0);
    }
    __syncthreads();

    bhalf8 af[4], bfr[4];
    #pragma unroll
    for (int i = 0; i < 4; ++i)
      af[i] = *(const bhalf8*)&As[(wy * 64 + i * 16 + mm) * TK + quad * 8];
    #pragma unroll
    for (int j = 0; j < 4; ++j)
      bfr[j] = *(const bhalf8*)&Bs[(wx * 64 + j * 16 + mm) * TK + quad * 8];
    #pragma unroll
    for (int i = 0; i < 4; ++i)
      #pragma unroll
      for (int j = 0; j < 4; ++j)
        acc[i][j] = __builtin_amdgcn_mfma_f32_16x16x32_bf16(af[i], bfr[j], acc[i][j], 0, 0, 0);
  }

  #pragma unroll
  for (int i = 0; i < 4; ++i) {
    const int row = row0 + wy * 64 + i * 16 + quad * 4;
    #pragma unroll
    for (int j = 0; j < 4; ++j) {
      const int col = wx * 64 + j * 16 + mm;
      if (col < Nreal) {
        #pragma unroll
        for (int r = 0; r < 4; ++r)
          Cpart[((size_t)ks * BL + row + r) * 80 + col] = acc[i][j][r];
      }
    }
  }
}

__global__ __launch_bounds__(256) void reduce_splitk(
    const float* __restrict__ Cpart, float* __restrict__ xd)
{
  const int i = (blockIdx.x * 256 + threadIdx.x) * 4;  // over BL*80
  float4 a = {0.f, 0.f, 0.f, 0.f};
  #pragma unroll
  for (int ks = 0; ks < KSPLIT; ++ks) {
    float4 v = *(const float4*)(Cpart + (size_t)ks * (BL * 80) + i);
    a.x += v.x; a.y += v.y; a.z += v.z; a.w += v.w;
  }
  *(float4*)(xd + i) = a;
}

// ================= fp32 -> bf16 transpose: out[Cpad][R] = in[R][C]^T =======
__global__ __launch_bounds__(256) void transpose_cvt(
    const float* __restrict__ in, __hip_bfloat16* __restrict__ out,
    int R, int C, int Cpad)
{
  __shared__ __hip_bfloat16 tile[32][33];
  const int c0 = blockIdx.x * 32, r0 = blockIdx.y * 32;
  const int tx = threadIdx.x & 31, ty = threadIdx.x >> 5;
  #pragma unroll
  for (int i = 0; i < 32; i += 8) {
    const int c = c0 + tx;
    float v = (c < C) ? in[(size_t)(r0 + ty + i) * C + c] : 0.f;
    tile[ty + i][tx] = __float2bfloat16(v);
  }
  __syncthreads();
  #pragma unroll
  for (int i = 0; i < 32; i += 8)
    out[(size_t)(c0 + ty + i) * R + r0 + tx] = tile[tx][ty + i];
}

__global__ __launch_bounds__(256) void cvt_bf16(
    const float* __restrict__ in, __hip_bfloat16* __restrict__ out)
{
  const int i = (blockIdx.x * 256 + threadIdx.x) * 4;
  float4 v = *(const float4*)(in + i);
  out[i]     = __float2bfloat16(v.x);
  out[i + 1] = __float2bfloat16(v.y);
  out[i + 2] = __float2bfloat16(v.z);
  out[i + 3] = __float2bfloat16(v.w);
}

// ============ causal depthwise conv (width 4) + SiLU -> bf16 ==========
__global__ __launch_bounds__(256) void conv_silu_kernel(
    const float* __restrict__ u_raw, const float* __restrict__ cw,
    const float* __restrict__ cb, __hip_bfloat16* __restrict__ ub)
{
  const int idx = blockIdx.x * 256 + threadIdx.x;
  const int d  = idx % D_INNER;
  const int bl = idx / D_INNER;
  const int l  = bl % LL;
  float acc = cb[d];
  #pragma unroll
  for (int k = 0; k < D_CONV; ++k) {
    const int ls = l - (D_CONV - 1) + k;
    if (ls >= 0) acc += u_raw[idx + (k - (D_CONV - 1)) * D_INNER] * cw[d * D_CONV + k];
  }
  const float s = acc / (1.f + __expf(-acc));
  ub[idx] = __float2bfloat16(s);
}

// ======== delta = softplus(xd[:, :48] @ W_dt + b_dt), fp32 ========
__global__ __launch_bounds__(256) void delta_kernel(
    const float* __restrict__ xd, const float* __restrict__ Wdt,
    const float* __restrict__ bdt, float* __restrict__ delta)
{
  __shared__ float Asr[16][DT_RANK];
  __shared__ float Ws[DT_RANK][256];
  const int n0 = blockIdx.x * 256;
  const int m0 = blockIdx.y * 16;
  const int tid = threadIdx.x;
  for (int f = tid; f < 16 * DT_RANK; f += 256)
    Asr[f / DT_RANK][f % DT_RANK] = xd[(size_t)(m0 + f / DT_RANK) * 80 + (f % DT_RANK)];
  for (int f = tid; f < DT_RANK * 256; f += 256)
    Ws[f >> 8][f & 255] = Wdt[(size_t)(f >> 8) * D_INNER + n0 + (f & 255)];
  __syncthreads();
  float acc[16];
  #pragma unroll
  for (int i = 0; i < 16; ++i) acc[i] = 0.f;
  for (int k = 0; k < DT_RANK; ++k) {
    const float w = Ws[k][tid];
    #pragma unroll
    for (int i = 0; i < 16; ++i) acc[i] += Asr[i][k] * w;
  }
  const float bb = bdt[n0 + tid];
  #pragma unroll
  for (int i = 0; i < 16; ++i) {
    const float v = acc[i] + bb;
    delta[(size_t)(m0 + i) * D_INNER + n0 + tid] =
        fmaxf(v, 0.f) + log1pf(__expf(-fabsf(v)));
  }
}

// ============== selective scan: 1 thread = 1 d, 16 states in regs ==========
// grid (NCHUNK, D_INNER/256, BB), block 256. Layout of prodA/localS:
// idx = ((c*BB + b)*D_INNER + d)*16 + n  (16 consecutive per thread).
__global__ __launch_bounds__(256) void scan_pass1(
    const float* __restrict__ delta, const ushort_t* __restrict__ ub,
    const float* __restrict__ xd, const float* __restrict__ A_log,
    float* __restrict__ prodA, float* __restrict__ localS)
{
  __shared__ float BC[CHUNK][32];   // B (0..15) | C (16..31) per t
  const int c = blockIdx.x, dg = blockIdx.y, b = blockIdx.z;
  const int d = dg * 256 + threadIdx.x;
  const int t0 = c * CHUNK;
  {
    const int t = threadIdx.x >> 3, q = threadIdx.x & 7;
    *(float4*)&BC[t][q * 4] =
        *(const float4*)(xd + ((size_t)b * LL + t0 + t) * 80 + DT_RANK + q * 4);
  }
  float Aneg[16];
  {
    #pragma unroll
    for (int i = 0; i < 4; ++i) {
      float4 v = *(const float4*)(A_log + (size_t)d * 16 + i * 4);
      Aneg[i*4+0] = -__expf(v.x); Aneg[i*4+1] = -__expf(v.y);
      Aneg[i*4+2] = -__expf(v.z); Aneg[i*4+3] = -__expf(v.w);
    }
  }
  __syncthreads();
  float s[16], pr[16];
  #pragma unroll
  for (int n = 0; n < 16; ++n) { s[n] = 0.f; pr[n] = 1.f; }
  const float*    dp = delta + ((size_t)b * LL + t0) * D_INNER + d;
  const ushort_t* up = ub    + ((size_t)b * LL + t0) * D_INNER + d;
  #pragma unroll 4
  for (int t = 0; t < CHUNK; ++t) {
    const float dt  = dp[(size_t)t * D_INNER];
    const float ut  = b2f(up[(size_t)t * D_INNER]);
    const float dtu = dt * ut;
    float Bv[16];
    #pragma unroll
    for (int i = 0; i < 4; ++i)
      *(float4*)&Bv[i * 4] = *(const float4*)&BC[t][i * 4];
    #pragma unroll
    for (int n = 0; n < 16; ++n) {
      const float da = __expf(dt * Aneg[n]);
      pr[n] *= da;
      s[n] = da * s[n] + dtu * Bv[n];
    }
  }
  const size_t obase = (((size_t)c * BB + b) * D_INNER + d) * 16;
  #pragma unroll
  for (int i = 0; i < 4; ++i) {
    *(float4*)&prodA[obase + i * 4]  = *(float4*)&pr[i * 4];
    *(float4*)&localS[obase + i * 4] = *(float4*)&s[i * 4];
  }
}

// in-place: localS becomes sIn (chunk-entry state)
__global__ __launch_bounds__(256) void scan_pass2(
    const float* __restrict__ prodA, float* __restrict__ sc)
{
  const int g = blockIdx.x * 256 + threadIdx.x;  // BB*D_INNER*16 lanes
  float s = 0.f;
  for (int c = 0; c < NCHUNK; ++c) {
    const size_t idx = (size_t)c * (BB * D_INNER * 16) + g;
    const float p = prodA[idx];
    const float l = sc[idx];
    sc[idx] = s;
    s = p * s + l;
  }
}

__global__ __launch_bounds__(256) void scan_pass3(
    const float* __restrict__ delta, const ushort_t* __restrict__ ub,
    const float* __restrict__ xd, const float* __restrict__ A_log,
    const float* __restrict__ sIn, const float* __restrict__ res,
    const float* __restrict__ Dp, __hip_bfloat16* __restrict__ y)
{
  __shared__ float BC[CHUNK][32];
  const int c = blockIdx.x, dg = blockIdx.y, b = blockIdx.z;
  const int d = dg * 256 + threadIdx.x;
  const int t0 = c * CHUNK;
  {
    const int t = threadIdx.x >> 3, q = threadIdx.x & 7;
    *(float4*)&BC[t][q * 4] =
        *(const float4*)(xd + ((size_t)b * LL + t0 + t) * 80 + DT_RANK + q * 4);
  }
  float Aneg[16];
  {
    #pragma unroll
    for (int i = 0; i < 4; ++i) {
      float4 v = *(const float4*)(A_log + (size_t)d * 16 + i * 4);
      Aneg[i*4+0] = -__expf(v.x); Aneg[i*4+1] = -__expf(v.y);
      Aneg[i*4+2] = -__expf(v.z); Aneg[i*4+3] = -__expf(v.w);
    }
  }
  __syncthreads();
  float s[16];
  const size_t obase = (((size_t)c * BB + b) * D_INNER + d) * 16;
  #pragma unroll
  for (int i = 0; i < 4; ++i)
    *(float4*)&s[i * 4] = *(const float4*)&sIn[obase + i * 4];
  const float Dpv = Dp[d];
  const float*    dp = delta + ((size_t)b * LL + t0) * D_INNER + d;
  const ushort_t* up = ub    + ((size_t)b * LL + t0) * D_INNER + d;
  const float*    rp = res   + ((size_t)b * LL + t0) * D_INNER + d;
  __hip_bfloat16* yp = y     + ((size_t)b * LL + t0) * D_INNER + d;
  #pragma unroll 4
  for (int t = 0; t < CHUNK; ++t) {
    const float dt  = dp[(size_t)t * D_INNER];
    const float ut  = b2f(up[(size_t)t * D_INNER]);
    const float r   = rp[(size_t)t * D_INNER];
    const float dtu = dt * ut;
    float Bv[16], Cv[16];
    #pragma unroll
    for (int i = 0; i < 4; ++i) {
      *(float4*)&Bv[i * 4] = *(const float4*)&BC[t][i * 4];
      *(float4*)&Cv[i * 4] = *(const float4*)&BC[t][16 + i * 4];
    }
    float yv = 0.f;
    #pragma unroll
    for (int n = 0; n < 16; ++n) {
      const float da = __expf(dt * Aneg[n]);
      s[n] = da * s[n] + dtu * Bv[n];
      yv += s[n] * Cv[n];
    }
    const float sr = r / (1.f + __expf(-r));
    yp[(size_t)t * D_INNER] = __float2bfloat16((yv + ut * Dpv) * sr);
  }
}

extern "C" void kernel_launch(void* const* d_in, const int* in_sizes, int n_in,
                              void* d_out, int out_size, void* d_ws, size_t ws_size,
                              hipStream_t stream) {
  const float* x      = (const float*)d_in[0];
  const float* W_in   = (const float*)d_in[1];
  const float* conv_w = (const float*)d_in[2];
  const float* conv_b = (const float*)d_in[3];
  const float* W_x    = (const float*)d_in[4];
  const float* W_dt   = (const float*)d_in[5];
  const float* b_dt   = (const float*)d_in[6];
  const float* A_log  = (const float*)d_in[7];
  const float* Dp     = (const float*)d_in[8];
  const float* W_out  = (const float*)d_in[9];
  float* out = (float*)d_out;

  // ---- workspace arena (float units), total 31,260,672 f = 125.0 MB ----
  float* ws     = (float*)d_ws;
  float* res    = ws;                        // 6291456
  float* delta  = ws + 6291456;              // 6291456
  float* uraw   = ws + 12582912;             // 6291456 (dead after conv)
  __hip_bfloat16* u_bf = (__hip_bfloat16*)(ws + 18874368);  // 3145728 f-slots
  float* xd     = ws + 22020096;             // 327680
  float* regC   = ws + 22347776;             // 3145728 (x_bf+WinT, later prodA)
  float* localS = ws + 25493504;             // 3145728 (becomes sIn in-place)
  float* xdpart = ws + 28639232;             // 2621440 (KSPLIT*BL*80)
  __hip_bfloat16* x_bf  = (__hip_bfloat16*)regC;               // dead after GEMM1
  __hip_bfloat16* WinT  = (__hip_bfloat16*)(regC + 1572864);   // dead after GEMM1
  float* prodA = regC;
  __hip_bfloat16* y_bf  = (__hip_bfloat16*)uraw;               // after conv
  __hip_bfloat16* WoutT = (__hip_bfloat16*)(uraw + 3145728);
  __hip_bfloat16* WxT   = (__hip_bfloat16*)(uraw + 3735552);

  // 1) casts/transposes
  cvt_bf16<<<(BL * D_MODEL) / 1024, 256, 0, stream>>>(x, x_bf);
  transpose_cvt<<<dim3(96, 24), 256, 0, stream>>>(W_in, WinT, 768, 3072, 3072);
  // 2) GEMM1: [u_raw | res] = x @ W_in
  gemm_bf16<<<dim3(24, 32), 256, 0, stream>>>(
      (const ushort_t*)x_bf, (const ushort_t*)WinT, uraw, res,
      D_INNER, D_INNER, D_INNER, BL, 2 * D_INNER, D_MODEL);
  // 3) conv + silu -> u bf16
  conv_silu_kernel<<<(BL * D_INNER) / 256, 256, 0, stream>>>(uraw, conv_w, conv_b, u_bf);
  // 4) weight transposes into dead u_raw
  transpose_cvt<<<dim3(4, 48), 256, 0, stream>>>(W_x, WxT, 1536, 80, 128);
  transpose_cvt<<<dim3(24, 48), 256, 0, stream>>>(W_out, WoutT, 1536, 768, 768);
  // 5) GEMM2 split-K: xd = u @ W_x
  gemm_bf16_splitk<<<dim3(KSPLIT, 32), 256, 0, stream>>>(
      (const ushort_t*)u_bf, (const ushort_t*)WxT, xdpart, 80, D_INNER, 6);
  reduce_splitk<<<(BL * 80) / 1024, 256, 0, stream>>>(xdpart, xd);
  // 6) delta
  delta_kernel<<<dim3(6, 256), 256, 0, stream>>>(xd, W_dt, b_dt, delta);
  // 7) scan
  scan_pass1<<<dim3(NCHUNK, 6, BB), 256, 0, stream>>>(
      delta, (const ushort_t*)u_bf, xd, A_log, prodA, localS);
  scan_pass2<<<(BB * D_INNER * 16) / 256, 256, 0, stream>>>(prodA, localS);
  scan_pass3<<<dim3(NCHUNK, 6, BB), 256, 0, stream>>>(
      delta, (const ushort_t*)u_bf, xd, A_log, localS, res, Dp, y_bf);
  // 8) GEMM3: out = y @ W_out
  gemm_bf16<<<dim3(6, 32), 256, 0, stream>>>(
      (const ushort_t*)y_bf, (const ushort_t*)WoutT, out, nullptr,
      1 << 30, D_MODEL, D_MODEL, BL, D_MODEL, D_INNER);
}